// Round 1
// baseline (14484.427 us; speedup 1.0000x reference)
//
#include <hip/hip_runtime.h>
#include <math.h>

#define NT 256

__device__ __forceinline__ float sigf(float x){ return 1.0f/(1.0f+expf(-x)); }

__launch_bounds__(NT, 1)
__global__ void kf_fwd(const float* __restrict__ a_seq, const float* __restrict__ h_obs,
  const float* __restrict__ Amat, const float* __restrict__ Cmat, const float* __restrict__ Bmat,
  const float* __restrict__ u_seq, const float* __restrict__ mask, const float* __restrict__ P0,
  const float* __restrict__ matQ, const float* __restrict__ matR,
  const float* __restrict__ Wx, const float* __restrict__ Wh, const float* __restrict__ gbias,
  const float* __restrict__ outW, const float* __restrict__ outb, float* __restrict__ out)
{
  constexpr int DZ=32, DA=16, DU=4, NK=8, GHH=64, DOBS=16, DIN=192, T=256, B=128;
  constexpr int LZ=33, LA=17;
  constexpr size_t BT=(size_t)B*T;
  const size_t off_zf=0;
  const size_t off_Pf=off_zf+BT*DZ;
  const size_t off_zl=off_Pf+BT*DZ*DZ;
  const size_t off_tr=off_zl+BT*DZ;
  const size_t off_zp=off_tr+BT*DZ*DZ;
  const size_t off_Pp=off_zp+BT*DZ;
  const size_t off_af=off_Pp+BT*DZ*DZ;
  const size_t off_ap=off_af+BT*DA;
  const size_t off_S =off_ap+BT*DA;
  const size_t off_al=off_S +BT*DA*DA;
  const size_t off_ai=off_al+BT*NK;
  const size_t off_R =off_ai+BT*NK;
  const size_t off_Q =off_R +DA*DA;

  __shared__ float P[DZ*LZ], Ak[DZ*LZ], IKCm[DZ*LZ], T1[DZ*LZ], T2[DZ*LZ], T3[DZ*LZ], Qm[DZ*LZ];
  __shared__ float Ck[DA*LZ], Cprev[DA*LZ], CPm[DA*LZ];
  __shared__ float Kg[DZ*LA], KgR[DZ*LA];
  __shared__ float Rm[DA*LA], Sm[DA*LA], Sinv[DA*LA], Linv[DA*LA];
  __shared__ float Bk[DZ*DU];
  __shared__ float zc[DZ], znew[DZ], zloc[DZ], zpred[DZ], ghs[GHH], hob[DOBS];
  __shared__ float xin[DIN], gx[DIN], ghl[DIN];
  __shared__ float zj[NK*DZ], aj[NK*DA], aprev[DA];
  __shared__ float ak[DA], uk[DU], rk[DA], ll[NK], lg[NK], alpha[NK];
  __shared__ float mval;

  const int tid = threadIdx.x;
  const int b = blockIdx.x;

  // ---------- init ----------
  for (int e=tid; e<DZ*DZ; e+=NT){
    int i=e>>5, j=e&31;
    float s=0.f;
    #pragma unroll
    for (int k=0;k<DZ;k++) s += matQ[i*DZ+k]*matQ[j*DZ+k];
    Qm[i*LZ+j] = s + (i==j?0.001f:0.0f);
    P[i*LZ+j]  = P0[e];
  }
  for (int e=tid; e<DA*DA; e+=NT){
    int i=e>>4, j=e&15;
    float s=0.f;
    #pragma unroll
    for (int k=0;k<DA;k++) s += matR[i*DA+k]*matR[j*DA+k];
    Rm[i*LA+j] = s + (i==j?0.001f:0.0f);
  }
  for (int e=tid; e<DA*DZ; e+=NT) Cprev[(e>>5)*LZ+(e&31)] = Cmat[e];   // C_matrices[0]
  if (tid<DZ) zc[tid]=0.f;
  if (tid<GHH) ghs[tid]=0.f;
  if (tid<DOBS) hob[tid]=h_obs[b*DOBS+tid];
  __syncthreads();
  if (b==0){
    for (int e=tid;e<DA*DA;e+=NT) out[off_R+e] = Rm[(e>>4)*LA+(e&15)];
    for (int e=tid;e<DZ*DZ;e+=NT) out[off_Q+e] = Qm[(e>>5)*LZ+(e&31)];
  }

  for (int t=0;t<T;t++){
    const size_t bt = (size_t)b*T + t;

    // A: per-step loads + zj[k][i] = A[k] @ z_prev
    if (tid<DA) ak[tid] = a_seq[bt*DA+tid];
    else if (tid<DA+DU) uk[tid-DA] = u_seq[bt*DU+(tid-DA)];
    else if (tid==DA+DU) mval = mask[bt];
    {
      int k=tid>>5, i=tid&31;
      const float* Ar = Amat + (size_t)(k*DZ+i)*DZ;
      float s=0.f;
      #pragma unroll
      for (int j=0;j<DZ;j++) s += Ar[j]*zc[j];
      zj[tid]=s;
    }
    __syncthreads();

    // B: aj[k][a] = C[k] @ zj[k] ; a_prev = C_prev @ z_prev
    if (tid < NK*DA){
      int k=tid>>4, a2=tid&15;
      const float* Cr = Cmat + (size_t)(k*DA+a2)*DZ;
      const float* zr = zj + k*DZ;
      float s=0.f;
      #pragma unroll
      for (int i=0;i<DZ;i++) s += Cr[i]*zr[i];
      aj[tid]=s;
    } else if (tid < NK*DA + DA){
      int a2 = tid - NK*DA;
      float s=0.f;
      #pragma unroll
      for (int i=0;i<DZ;i++) s += Cprev[a2*LZ+i]*zc[i];
      aprev[a2]=s;
    }
    __syncthreads();

    // C: x_in assembly ; log_lik
    if (tid < DIN){
      float v;
      if (tid<DA) v=aprev[tid];
      else if (tid<DA+DOBS) v=hob[tid-DA];
      else if (tid<DA+DOBS+DZ) v=zc[tid-DA-DOBS];
      else v=aj[tid-(DA+DOBS+DZ)];
      xin[tid]=v;
    } else if (tid < DIN+NK){
      int k=tid-DIN;
      float s=0.f;
      #pragma unroll
      for (int a2=0;a2<DA;a2++){ float d=ak[a2]-aj[k*DA+a2]; s+=d*d; }
      ll[k]=-s;
    }
    __syncthreads();

    // D: GRU matvecs ; alpha_imm softmax -> global
    if (tid < DIN){
      float g = gbias[tid];
      #pragma unroll 8
      for (int i=0;i<DIN;i++) g += xin[i]*Wx[i*DIN+tid];
      gx[tid]=g;
      float gl=0.f;
      #pragma unroll 8
      for (int i=0;i<GHH;i++) gl += ghs[i]*Wh[i*DIN+tid];
      ghl[tid]=gl;
    } else if (tid < DIN+NK){
      int k=tid-DIN;
      float m8=ll[0];
      #pragma unroll
      for (int j=1;j<NK;j++) m8=fmaxf(m8,ll[j]);
      float ssum=0.f, ek=0.f;
      #pragma unroll
      for (int j=0;j<NK;j++){ float e2=expf(ll[j]-m8); ssum+=e2; if(j==k) ek=e2; }
      out[off_ai + bt*NK + k] = ek/ssum*mval;
    }
    __syncthreads();

    // E: GRU gates (in-place gh update; each thread touches only its own j)
    if (tid < GHH){
      float r  = sigf(gx[tid]+ghl[tid]);
      float zg = sigf(gx[GHH+tid]+ghl[GHH+tid]);
      float n  = tanhf(gx[2*GHH+tid] + r*ghl[2*GHH+tid]);
      ghs[tid] = (1.f-zg)*n + zg*ghs[tid];
    }
    __syncthreads();

    // F: logits
    if (tid < NK){
      float s = outb[tid];
      #pragma unroll
      for (int j=0;j<GHH;j++) s += ghs[j]*outW[j*NK+tid];
      lg[tid]=s;
    }
    __syncthreads();

    // G: alpha softmax (TEMP=1) -> LDS + global
    if (tid < NK){
      float m8=lg[0];
      #pragma unroll
      for (int j=1;j<NK;j++) m8=fmaxf(m8,lg[j]);
      float ssum=0.f, ek=0.f;
      #pragma unroll
      for (int j=0;j<NK;j++){ float e2=expf(lg[j]-m8); ssum+=e2; if(j==tid) ek=e2; }
      float av = ek/ssum;
      alpha[tid]=av;
      out[off_al + bt*NK + tid] = av;
    }
    __syncthreads();

    // H: blends A_k, C_k, B_k
    #pragma unroll
    for (int rep=0;rep<4;rep++){
      int e=tid+rep*NT;
      float s=0.f;
      #pragma unroll
      for (int k=0;k<NK;k++) s += alpha[k]*Amat[k*DZ*DZ+e];
      Ak[(e>>5)*LZ+(e&31)]=s;
    }
    #pragma unroll
    for (int rep=0;rep<2;rep++){
      int e=tid+rep*NT;
      float s=0.f;
      #pragma unroll
      for (int k=0;k<NK;k++) s += alpha[k]*Cmat[k*DA*DZ+e];
      Ck[(e>>5)*LZ+(e&31)]=s;
    }
    if (tid < DZ*DU){
      float s=0.f;
      #pragma unroll
      for (int k=0;k<NK;k++) s += alpha[k]*Bmat[k*DZ*DU+tid];
      Bk[tid]=s;
    }
    __syncthreads();

    // I: z = A_k @ z_prev ; CP = C_k @ P
    if (tid<DZ){
      float s=0.f;
      #pragma unroll
      for (int j=0;j<DZ;j++) s += Ak[tid*LZ+j]*zc[j];
      znew[tid]=s;
    }
    #pragma unroll
    for (int rep=0;rep<2;rep++){
      int e=tid+rep*NT; int a2=e>>5, i=e&31;
      float s=0.f;
      #pragma unroll
      for (int j=0;j<DZ;j++) s += Ck[a2*LZ+j]*P[j*LZ+i];
      CPm[a2*LZ+i]=s;
    }
    __syncthreads();

    // J: S = CP @ C_k^T + R + 1e-4 I ; r_k
    {
      int a2=tid>>4, c2=tid&15;
      float s=0.f;
      #pragma unroll
      for (int i=0;i<DZ;i++) s += CPm[a2*LZ+i]*Ck[c2*LZ+i];
      Sm[a2*LA+c2] = s + Rm[a2*LA+c2] + (a2==c2?1e-4f:0.f);
    }
    if (tid<DA){
      float s=0.f;
      #pragma unroll
      for (int i=0;i<DZ;i++) s += Ck[tid*LZ+i]*znew[i];
      rk[tid]=ak[tid]-s;
    }
    __syncthreads();

    // K: wave0 -> chol16(S) + L^{-1} in registers; waves 1-3 -> write S out
    if (tid < 64){
      int lane=tid;
      int row = lane<DA ? lane : DA-1;
      float Sr[16], Lr[16];
      #pragma unroll
      for (int j=0;j<16;j++) Sr[j]=Sm[row*LA+j];
      #pragma unroll
      for (int c=0;c<16;c++){
        float v=Sr[c];
        #pragma unroll
        for (int k=0;k<c;k++) v -= Lr[k]*__shfl(Lr[k],c);
        float d=__shfl(v,c);
        float sq=sqrtf(d);
        float inv=1.0f/sq;
        Lr[c] = (lane==c)? sq : v*inv;
      }
      float Li[16];
      #pragma unroll
      for (int r=0;r<16;r++){
        float tv = (lane==r)?1.0f:0.0f;
        #pragma unroll
        for (int k=0;k<r;k++) tv -= __shfl(Lr[k],r)*Li[k];
        float dr = __shfl(Lr[r],r);
        Li[r] = tv/dr;
      }
      if (lane<16){
        #pragma unroll
        for (int r=0;r<16;r++) Linv[r*LA+lane]=Li[r];
      }
    } else {
      for (int e=tid-64; e<DA*DA; e+=NT-64)
        out[off_S + bt*DA*DA + e] = Sm[(e>>4)*LA+(e&15)];
    }
    __syncthreads();

    // L: Sinv = Linv^T @ Linv
    {
      int a2=tid>>4, b2=tid&15;
      float s=0.f;
      #pragma unroll
      for (int k=0;k<16;k++) s += Linv[k*LA+a2]*Linv[k*LA+b2];
      Sinv[a2*LA+b2]=s;
    }
    __syncthreads();

    // M: Kg = CP^T @ Sinv, masked
    #pragma unroll
    for (int rep=0;rep<2;rep++){
      int e=tid+rep*NT; int i=e>>4, a2=e&15;
      float s=0.f;
      #pragma unroll
      for (int b2=0;b2<DA;b2++) s += CPm[b2*LZ+i]*Sinv[b2*LA+a2];
      Kg[i*LA+a2]=s*mval;
    }
    __syncthreads();

    // N: IKC = I - Kg C_k ; KgR = Kg @ R ; z_loc
    #pragma unroll
    for (int rep=0;rep<4;rep++){
      int e=tid+rep*NT; int i=e>>5, j=e&31;
      float s=(i==j)?1.0f:0.0f;
      #pragma unroll
      for (int a2=0;a2<DA;a2++) s -= Kg[i*LA+a2]*Ck[a2*LZ+j];
      IKCm[i*LZ+j]=s;
    }
    #pragma unroll
    for (int rep=0;rep<2;rep++){
      int e=tid+rep*NT; int i=e>>4, a2=e&15;
      float s=0.f;
      #pragma unroll
      for (int b2=0;b2<DA;b2++) s += Kg[i*LA+b2]*Rm[b2*LA+a2];
      KgR[i*LA+a2]=s;
    }
    if (tid<DZ){
      float s=znew[tid];
      #pragma unroll
      for (int a2=0;a2<DA;a2++) s += Kg[tid*LA+a2]*rk[a2];
      zloc[tid]=s;
    }
    __syncthreads();

    // O: T1 = IKC @ P ; T2 = KgR @ Kg^T
    #pragma unroll
    for (int rep=0;rep<4;rep++){
      int e=tid+rep*NT; int i=e>>5, j=e&31;
      float s=0.f;
      #pragma unroll
      for (int a2=0;a2<DZ;a2++) s += IKCm[i*LZ+a2]*P[a2*LZ+j];
      T1[i*LZ+j]=s;
      float s2=0.f;
      #pragma unroll
      for (int a2=0;a2<DA;a2++) s2 += KgR[i*LA+a2]*Kg[j*LA+a2];
      T2[i*LZ+j]=s2;
    }
    __syncthreads();

    // P: T3 = T1 @ IKC^T + T2  (raw P_f)
    #pragma unroll
    for (int rep=0;rep<4;rep++){
      int e=tid+rep*NT; int i=e>>5, j=e&31;
      float s=T2[i*LZ+j];
      #pragma unroll
      for (int a2=0;a2<DZ;a2++) s += T1[i*LZ+a2]*IKCm[j*LZ+a2];
      T3[i*LZ+j]=s;
    }
    __syncthreads();

    // Q: T1 = 0.5(T3+T3^T)+0.001I (final P_f) ; z_filt/z_loc out ; a_filt out
    #pragma unroll
    for (int rep=0;rep<4;rep++){
      int e=tid+rep*NT; int i=e>>5, j=e&31;
      T1[i*LZ+j] = 0.5f*(T3[i*LZ+j]+T3[j*LZ+i]) + (i==j?0.001f:0.f);
    }
    if (tid<DZ){
      out[off_zf+bt*DZ+tid]=zloc[tid];
      out[off_zl+bt*DZ+tid]=zloc[tid];
    } else if (tid<DZ+DA){
      int a2=tid-DZ;
      float s=0.f;
      #pragma unroll
      for (int i=0;i<DZ;i++) s += Ck[a2*LZ+i]*zloc[i];
      out[off_af+bt*DA+a2]=s;
    }
    __syncthreads();

    // R/S: wave0 chol32(P_f)->T2 ; others: T3 = A_k @ P_f, P_f out, z_pred
    if (tid < 64){
      int lane=tid;
      int row = lane<DZ ? lane : DZ-1;
      float Pr[32], Lr[32];
      #pragma unroll
      for (int j=0;j<32;j++) Pr[j]=T1[row*LZ+j];
      #pragma unroll
      for (int c=0;c<32;c++){
        float v=Pr[c];
        #pragma unroll
        for (int k=0;k<c;k++) v -= Lr[k]*__shfl(Lr[k],c);
        float d=__shfl(v,c);
        float sq=sqrtf(d);
        float inv=1.0f/sq;
        Lr[c]=(lane==c)?sq:v*inv;
      }
      if (lane<DZ){
        #pragma unroll
        for (int j=0;j<32;j++) T2[lane*LZ+j] = (j<=lane)?Lr[j]:0.0f;
      }
    } else {
      for (int e=tid-64; e<DZ*DZ; e+=NT-64){
        int i=e>>5, j=e&31;
        float s=0.f;
        #pragma unroll
        for (int a2=0;a2<DZ;a2++) s += Ak[i*LZ+a2]*T1[a2*LZ+j];
        T3[i*LZ+j]=s;
      }
      for (int e=tid-64; e<DZ*DZ; e+=NT-64)
        out[off_Pf+bt*DZ*DZ+e] = T1[(e>>5)*LZ+(e&31)];
      if (tid<64+DZ){
        int i=tid-64;
        float s=0.f;
        #pragma unroll
        for (int j=0;j<DZ;j++) s += Ak[i*LZ+j]*zloc[j];
        #pragma unroll
        for (int u2=0;u2<DU;u2++) s += Bk[i*DU+u2]*uk[u2];
        zpred[i]=s;
      }
    }
    __syncthreads();

    // T: T1 = T3 @ A_k^T + Q (raw P_p) ; tril out ; a_pred ; z_pred out
    #pragma unroll
    for (int rep=0;rep<4;rep++){
      int e=tid+rep*NT; int i=e>>5, j=e&31;
      float s=Qm[i*LZ+j];
      #pragma unroll
      for (int a2=0;a2<DZ;a2++) s += T3[i*LZ+a2]*Ak[j*LZ+a2];
      T1[i*LZ+j]=s;
      out[off_tr+bt*DZ*DZ+e]=T2[i*LZ+j];
    }
    if (tid<DA){
      float s=0.f;
      #pragma unroll
      for (int i=0;i<DZ;i++) s += Ck[tid*LZ+i]*zpred[i];
      out[off_ap+bt*DA+tid]=s;
    } else if (tid<DA+DZ){
      out[off_zp+bt*DZ+(tid-DA)]=zpred[tid-DA];
    }
    __syncthreads();

    // U: P = 0.5(T1+T1^T)+0.001I -> carry + P_p out ; z carry ; C_prev = C_k
    #pragma unroll
    for (int rep=0;rep<4;rep++){
      int e=tid+rep*NT; int i=e>>5, j=e&31;
      float v = 0.5f*(T1[i*LZ+j]+T1[j*LZ+i]) + (i==j?0.001f:0.f);
      P[i*LZ+j]=v;
      out[off_Pp+bt*DZ*DZ+e]=v;
    }
    if (tid<DZ) zc[tid]=zloc[tid];
    #pragma unroll
    for (int rep=0;rep<2;rep++){
      int e=tid+rep*NT;
      Cprev[(e>>5)*LZ+(e&31)] = Ck[(e>>5)*LZ+(e&31)];
    }
    __syncthreads();
  }
}

extern "C" void kernel_launch(void* const* d_in, const int* in_sizes, int n_in,
                              void* d_out, int out_size, void* d_ws, size_t ws_size,
                              hipStream_t stream) {
  kf_fwd<<<128, NT, 0, stream>>>(
    (const float*)d_in[0],  // a_seq
    (const float*)d_in[1],  // h_obs
    (const float*)d_in[2],  // A_matrices
    (const float*)d_in[3],  // C_matrices
    (const float*)d_in[4],  // B_matrices
    (const float*)d_in[5],  // u_seq
    (const float*)d_in[6],  // mask
    (const float*)d_in[7],  // P_0
    (const float*)d_in[8],  // mat_Q
    (const float*)d_in[9],  // mat_R
    (const float*)d_in[10], // gru_Wx
    (const float*)d_in[11], // gru_Wh
    (const float*)d_in[12], // gru_b
    (const float*)d_in[13], // out_W
    (const float*)d_in[14], // out_b
    (float*)d_out);
}

// Round 2
// 9976.929 us; speedup vs baseline: 1.4518x; 1.4518x over previous
//
#include <hip/hip_runtime.h>
#include <math.h>

#define NT 512

__device__ __forceinline__ float sigf(float x){ return 1.0f/(1.0f+expf(-x)); }

__launch_bounds__(NT, 1)
__global__ void kf_fwd(const float* __restrict__ a_seq, const float* __restrict__ h_obs,
  const float* __restrict__ Amat, const float* __restrict__ Cmat, const float* __restrict__ Bmat,
  const float* __restrict__ u_seq, const float* __restrict__ mask, const float* __restrict__ P0,
  const float* __restrict__ matQ, const float* __restrict__ matR,
  const float* __restrict__ Wx, const float* __restrict__ Wh, const float* __restrict__ gbias,
  const float* __restrict__ outW, const float* __restrict__ outb, float* __restrict__ out)
{
  constexpr int DZ=32, DA=16, NK=8, T=256, B=128;
  constexpr int LZ=33, LA=17;
  constexpr size_t BT=(size_t)B*T;
  const size_t off_zf=0;
  const size_t off_Pf=off_zf+BT*DZ;
  const size_t off_zl=off_Pf+BT*DZ*DZ;
  const size_t off_tr=off_zl+BT*DZ;
  const size_t off_zp=off_tr+BT*DZ*DZ;
  const size_t off_Pp=off_zp+BT*DZ;
  const size_t off_af=off_Pp+BT*DZ*DZ;
  const size_t off_ap=off_af+BT*DA;
  const size_t off_S =off_ap+BT*DA;
  const size_t off_al=off_S +BT*DA*DA;
  const size_t off_ai=off_al+BT*NK;
  const size_t off_R =off_ai+BT*NK;
  const size_t off_Q =off_R +DA*DA;

  // weights resident in LDS
  __shared__ float sA[NK*DZ*LZ];   // [k][i][j] padded 33
  __shared__ float sC[NK*DA*LZ];   // [k][a][i] padded 33
  __shared__ float sBm[NK*DZ*4];
  __shared__ float souW[64*8];
  __shared__ float sgb[192];
  __shared__ float soutb[8];
  // work matrices
  __shared__ float P[DZ*LZ], Ak[DZ*LZ], IKCm[DZ*LZ], T1[DZ*LZ], T2[DZ*LZ], T3[DZ*LZ], Qm[DZ*LZ];
  __shared__ float Ck[DA*LZ], Cprev[DA*LZ], CPm[DA*LZ];
  __shared__ float Kg[DZ*LA], KgR[DZ*LA];
  __shared__ float Rm[DA*LA], Sm[DA*LA], Sinv[DA*LA], Linv[DA*LA];
  __shared__ float Bk[DZ*4];
  __shared__ float zc[DZ], znew[DZ], zloc[DZ], zpred[DZ], ghs[64];
  __shared__ float xin[192], gxp[4*192], ghlv[192];
  __shared__ float zj[NK*DZ], aj[NK*DA];
  __shared__ float ak[DA], uk[4], rk[DA], ll[NK], alpha8[NK];
  __shared__ float mval;

  const int tid = threadIdx.x;
  const int b = blockIdx.x;

  // ---------- init: stage weights into LDS ----------
  for (int e=tid; e<NK*DZ*DZ; e+=NT){ int k=e>>10, i=(e>>5)&31, j=e&31; sA[(k*DZ+i)*LZ+j]=Amat[e]; }
  for (int e=tid; e<NK*DA*DZ; e+=NT){ int k=e>>9, a=(e>>5)&15, i=e&31; sC[(k*DA+a)*LZ+i]=Cmat[e]; }
  for (int e=tid; e<NK*DZ*4; e+=NT) sBm[e]=Bmat[e];
  if (tid<512) souW[tid]=outW[tid];
  if (tid<192) sgb[tid]=gbias[tid];
  if (tid<8)   soutb[tid]=outb[tid];
  for (int e=tid; e<DZ*DZ; e+=NT){
    int i=e>>5, j=e&31;
    float s=0.f;
    #pragma unroll
    for (int k=0;k<DZ;k++) s += matQ[i*DZ+k]*matQ[j*DZ+k];
    Qm[i*LZ+j] = s + (i==j?0.001f:0.0f);
    P[i*LZ+j]  = P0[e];
  }
  for (int e=tid; e<DA*DA; e+=NT){
    int i=e>>4, j=e&15;
    float s=0.f;
    #pragma unroll
    for (int k=0;k<DA;k++) s += matR[i*DA+k]*matR[j*DA+k];
    Rm[i*LA+j] = s + (i==j?0.001f:0.0f);
  }
  for (int e=tid; e<DA*DZ; e+=NT){ int a=e>>5, i=e&31; Cprev[a*LZ+i]=Cmat[e]; }  // C_matrices[0]
  if (tid<DZ) zc[tid]=0.f;
  if (tid<64) ghs[tid]=0.f;
  if (tid<16) xin[16+tid]=h_obs[b*16+tid];   // h_obs slice of x_in, constant
  __syncthreads();
  if (b==0){
    for (int e=tid;e<DA*DA;e+=NT) out[off_R+e] = Rm[(e>>4)*LA+(e&15)];
    for (int e=tid;e<DZ*DZ;e+=NT) out[off_Q+e] = Qm[(e>>5)*LZ+(e&31)];
  }

  for (int t=0;t<T;t++){
    const size_t bt = (size_t)b*T + t;

    // ---- A: zj (LDS A) | ghl = ghs@Wh | aprev->xin | xin[32:64]=zc | ak/uk/mask loads ----
    if (tid<256){
      int k=tid>>5, i=tid&31;
      const float* Ar=&sA[(k*DZ+i)*LZ];
      float s=0.f;
      #pragma unroll
      for (int j=0;j<DZ;j++) s += Ar[j]*zc[j];
      zj[tid]=s;
    } else if (tid<448){
      int c=tid-256;
      const float* wp=Wh+c;
      float s=0.f;
      #pragma unroll 16
      for (int i=0;i<64;i++) s += ghs[i]*wp[i*192];
      ghlv[c]=s;
    } else if (tid<464){
      int a=tid-448;
      float s=0.f;
      #pragma unroll
      for (int i=0;i<DZ;i++) s += Cprev[a*LZ+i]*zc[i];
      xin[a]=s;
    } else if (tid<496){
      int q=tid-464;
      if (q<16) ak[q]=a_seq[bt*DA+q];
      else if (q<20) uk[q-16]=u_seq[bt*4+(q-16)];
      else if (q==20) mval=mask[bt];
      xin[32+q]=zc[q];
    }
    __syncthreads();

    // ---- B: gx partials over inputs 0..63 | aj (and xin[64:192]) ----
    if (tid<384){
      int h=(tid>=192); int c=tid-h*192;
      const float* wp=Wx+(h*32)*192+c;
      float s=0.f;
      #pragma unroll 16
      for (int i=0;i<32;i++) s += xin[h*32+i]*wp[i*192];
      gxp[h*192+c]=s;
    } else {
      int e=tid-384; int k=e>>4, a=e&15;
      const float* Cr=&sC[(k*DA+a)*LZ];
      const float* zr=&zj[k*DZ];
      float s=0.f;
      #pragma unroll
      for (int i=0;i<DZ;i++) s += Cr[i]*zr[i];
      aj[e]=s; xin[64+e]=s;
    }
    __syncthreads();

    // ---- D: gx partials over inputs 64..191 | ll + alpha_imm (one wave, in-wave) ----
    if (tid<384){
      int h=(tid>=192); int c=tid-h*192;
      const float* wp=Wx+(64+h*64)*192+c;
      float s=0.f;
      #pragma unroll 16
      for (int i=0;i<64;i++) s += xin[64+h*64+i]*wp[i*192];
      gxp[(2+h)*192+c]=s;
    } else if (tid<392){
      int k=tid-384;
      float s=0.f;
      #pragma unroll
      for (int a=0;a<DA;a++){ float d=ak[a]-aj[k*DA+a]; s+=d*d; }
      ll[k]=-s;
      // same wave: all 8 writes complete in-order before reads
      float m8=ll[0];
      #pragma unroll
      for (int j=1;j<NK;j++) m8=fmaxf(m8,ll[j]);
      float ssum=0.f, ek=0.f;
      #pragma unroll
      for (int j=0;j<NK;j++){ float e2=expf(ll[j]-m8); ssum+=e2; if(j==k) ek=e2; }
      out[off_ai + bt*NK + k] = ek/ssum*mval;
    }
    __syncthreads();

    // ---- EFG (wave0): GRU gates -> logits -> alpha softmax, no internal barriers ----
    if (tid<64){
      int j=tid;
      float gr = sgb[j]     + gxp[j]     + gxp[192+j] + gxp[384+j] + gxp[576+j];
      float gz = sgb[64+j]  + gxp[64+j]  + gxp[256+j] + gxp[448+j] + gxp[640+j];
      float gn = sgb[128+j] + gxp[128+j] + gxp[320+j] + gxp[512+j] + gxp[704+j];
      float r  = sigf(gr+ghlv[j]);
      float zg = sigf(gz+ghlv[64+j]);
      float n  = tanhf(gn + r*ghlv[128+j]);
      ghs[j] = (1.f-zg)*n + zg*ghs[j];
      if (tid<8){
        float s=soutb[tid];
        #pragma unroll
        for (int q=0;q<64;q++) s += ghs[q]*souW[q*8+tid];
        float m8=s;
        m8=fmaxf(m8,__shfl_xor(m8,1));
        m8=fmaxf(m8,__shfl_xor(m8,2));
        m8=fmaxf(m8,__shfl_xor(m8,4));
        float e2=expf(s-m8);
        float ss=e2;
        ss+=__shfl_xor(ss,1); ss+=__shfl_xor(ss,2); ss+=__shfl_xor(ss,4);
        float av=e2/ss;
        alpha8[tid]=av;
        out[off_al + bt*NK + tid] = av;
      }
    }
    __syncthreads();

    // ---- H: blends from LDS ----
    #pragma unroll
    for (int rep=0;rep<2;rep++){
      int e=tid+rep*NT; int i=e>>5, j=e&31;
      float s=0.f;
      #pragma unroll
      for (int k=0;k<NK;k++) s += alpha8[k]*sA[(k*DZ+i)*LZ+j];
      Ak[i*LZ+j]=s;
    }
    {
      int a=tid>>5, i=tid&31;
      float s=0.f;
      #pragma unroll
      for (int k=0;k<NK;k++) s += alpha8[k]*sC[(k*DA+a)*LZ+i];
      Ck[a*LZ+i]=s;
    }
    if (tid<128){
      float s=0.f;
      #pragma unroll
      for (int k=0;k<NK;k++) s += alpha8[k]*sBm[k*128+tid];
      Bk[tid]=s;
    }
    __syncthreads();

    // ---- I: CP = Ck@P | znew = Ak@zc ----
    {
      int a=tid>>5, i=tid&31;
      float s=0.f;
      #pragma unroll
      for (int j=0;j<DZ;j++) s += Ck[a*LZ+j]*P[j*LZ+i];
      CPm[a*LZ+i]=s;
    }
    if (tid<DZ){
      float s=0.f;
      #pragma unroll
      for (int j=0;j<DZ;j++) s += Ak[tid*LZ+j]*zc[j];
      znew[tid]=s;
    }
    __syncthreads();

    // ---- J: S = CP@Ck^T + R + 1e-4 I | rk ----
    if (tid<256){
      int a=tid>>4, c=tid&15;
      float s=0.f;
      #pragma unroll
      for (int i=0;i<DZ;i++) s += CPm[a*LZ+i]*Ck[c*LZ+i];
      Sm[a*LA+c]=s+Rm[a*LA+c]+(a==c?1e-4f:0.f);
    } else if (tid<272){
      int a=tid-256;
      float s=0.f;
      #pragma unroll
      for (int i=0;i<DZ;i++) s += Ck[a*LZ+i]*znew[i];
      rk[a]=ak[a]-s;
    }
    __syncthreads();

    // ---- K: wave0 chol16 + Linv | S out ----
    if (tid<64){
      int lane=tid; int row=lane<DA?lane:DA-1;
      float Sr[16], Lr[16];
      #pragma unroll
      for (int j2=0;j2<16;j2++) Sr[j2]=Sm[row*LA+j2];
      #pragma unroll
      for (int c=0;c<16;c++){
        float v=Sr[c];
        #pragma unroll
        for (int k=0;k<c;k++) v -= Lr[k]*__shfl(Lr[k],c);
        float d=__shfl(v,c);
        float inv=rsqrtf(d);
        Lr[c]=(lane==c)?d*inv:v*inv;
      }
      float Li[16];
      #pragma unroll
      for (int r2=0;r2<16;r2++){
        float tv=(lane==r2)?1.f:0.f;
        #pragma unroll
        for (int k=0;k<r2;k++) tv -= __shfl(Lr[k],r2)*Li[k];
        float dr=__shfl(Lr[r2],r2);
        Li[r2]=tv/dr;
      }
      if (lane<16){
        #pragma unroll
        for (int r2=0;r2<16;r2++) Linv[r2*LA+lane]=Li[r2];
      }
    } else if (tid<320){
      int e=tid-64;
      out[off_S + bt*256 + e] = Sm[(e>>4)*LA+(e&15)];
    }
    __syncthreads();

    // ---- L: Sinv = Linv^T Linv ----
    if (tid<256){
      int a=tid>>4, b2=tid&15;
      float s=0.f;
      #pragma unroll
      for (int k=0;k<16;k++) s += Linv[k*LA+a]*Linv[k*LA+b2];
      Sinv[a*LA+b2]=s;
    }
    __syncthreads();

    // ---- M: Kg = CP^T @ Sinv (masked) ----
    {
      int i=tid>>4, a=tid&15;
      float s=0.f;
      #pragma unroll
      for (int b2=0;b2<DA;b2++) s += CPm[b2*LZ+i]*Sinv[b2*LA+a];
      Kg[i*LA+a]=s*mval;
    }
    __syncthreads();

    // ---- N: IKC | KgR | zloc ----
    #pragma unroll
    for (int rep=0;rep<2;rep++){
      int e=tid+rep*NT; int i=e>>5, j=e&31;
      float s=(i==j)?1.f:0.f;
      #pragma unroll
      for (int a=0;a<DA;a++) s -= Kg[i*LA+a]*Ck[a*LZ+j];
      IKCm[i*LZ+j]=s;
    }
    {
      int i=tid>>4, a=tid&15;
      float s=0.f;
      #pragma unroll
      for (int b2=0;b2<DA;b2++) s += Kg[i*LA+b2]*Rm[b2*LA+a];
      KgR[i*LA+a]=s;
    }
    if (tid<DZ){
      float s=znew[tid];
      #pragma unroll
      for (int a=0;a<DA;a++) s += Kg[tid*LA+a]*rk[a];
      zloc[tid]=s;
    }
    __syncthreads();

    // ---- OP: wave-private rows: T1 = IKC@P ; T3 = T1@IKC^T + KgR@Kg^T (raw Pf) ----
    {
      int wv=tid>>6, lane=tid&63;
      #pragma unroll
      for (int r2=0;r2<2;r2++){
        int row=wv*4+r2*2+(lane>>5);
        int j=lane&31;
        float s=0.f;
        #pragma unroll
        for (int a=0;a<DZ;a++) s += IKCm[row*LZ+a]*P[a*LZ+j];
        T1[row*LZ+j]=s;
      }
      #pragma unroll
      for (int r2=0;r2<2;r2++){
        int row=wv*4+r2*2+(lane>>5);
        int j=lane&31;
        float s=0.f;
        #pragma unroll
        for (int a=0;a<DZ;a++) s += T1[row*LZ+a]*IKCm[j*LZ+a];
        #pragma unroll
        for (int b2=0;b2<DA;b2++) s += KgR[row*LA+b2]*Kg[j*LA+b2];
        T3[row*LZ+j]=s;
      }
    }
    __syncthreads();

    // ---- R: wave0 chol32(sym Pf)->T2 | waves4-7: M3=Ak@Pf, Ppraw=M3@Ak^T+Q -> IKCm
    //         waves1-3: Pf out (sym on the fly), zf/zl/af/zpred outs ----
    {
      int wv=tid>>6, lane=tid&63;
      if (wv==0){
        int row=lane<DZ?lane:DZ-1;
        float Pr[32], Lr[32];
        #pragma unroll
        for (int j=0;j<32;j++) Pr[j]=0.5f*(T3[row*LZ+j]+T3[j*LZ+row])+(row==j?0.001f:0.f);
        #pragma unroll
        for (int c=0;c<32;c++){
          float v=Pr[c];
          #pragma unroll
          for (int k=0;k<c;k++) v -= Lr[k]*__shfl(Lr[k],c);
          float d=__shfl(v,c);
          float inv=rsqrtf(d);
          Lr[c]=(lane==c)?d*inv:v*inv;
        }
        if (lane<DZ){
          #pragma unroll
          for (int j=0;j<32;j++) T2[lane*LZ+j]=(j<=lane)?Lr[j]:0.f;
        }
      } else if (wv>=4){
        #pragma unroll
        for (int r2=0;r2<4;r2++){
          int row=(wv-4)*8+r2*2+(lane>>5);
          int j=lane&31;
          float s=0.f;
          #pragma unroll
          for (int a=0;a<DZ;a++){
            float pf=0.5f*(T3[a*LZ+j]+T3[j*LZ+a])+(a==j?0.001f:0.f);
            s += Ak[row*LZ+a]*pf;
          }
          T1[row*LZ+j]=s;
        }
        #pragma unroll
        for (int r2=0;r2<4;r2++){
          int row=(wv-4)*8+r2*2+(lane>>5);
          int j=lane&31;
          float s=Qm[row*LZ+j];
          #pragma unroll
          for (int a=0;a<DZ;a++) s += T1[row*LZ+a]*Ak[j*LZ+a];
          IKCm[row*LZ+j]=s;
        }
      } else {
        int e0=tid-64;
        for (int e=e0;e<1024;e+=192){
          int i=e>>5, j=e&31;
          out[off_Pf+bt*1024+e]=0.5f*(T3[i*LZ+j]+T3[j*LZ+i])+(i==j?0.001f:0.f);
        }
        if (tid<96){
          int i=tid-64;
          out[off_zf+bt*DZ+i]=zloc[i];
          out[off_zl+bt*DZ+i]=zloc[i];
        } else if (tid<112){
          int a=tid-96;
          float s=0.f;
          #pragma unroll
          for (int i=0;i<DZ;i++) s += Ck[a*LZ+i]*zloc[i];
          out[off_af+bt*DA+a]=s;
        } else if (tid<144){
          int i=tid-112;
          float s=0.f;
          #pragma unroll
          for (int j=0;j<DZ;j++) s += Ak[i*LZ+j]*zloc[j];
          #pragma unroll
          for (int u2=0;u2<4;u2++) s += Bk[i*4+u2]*uk[u2];
          zpred[i]=s;
          out[off_zp+bt*DZ+i]=s;
        }
      }
    }
    __syncthreads();

    // ---- U: P = sym(Ppraw)+.001I carry + Pp out | tril out | ap | zc carry | Cprev=Ck ----
    #pragma unroll
    for (int rep=0;rep<2;rep++){
      int e=tid+rep*NT; int i=e>>5, j=e&31;
      float v=0.5f*(IKCm[i*LZ+j]+IKCm[j*LZ+i])+(i==j?0.001f:0.f);
      P[i*LZ+j]=v;
      out[off_Pp+bt*1024+e]=v;
      out[off_tr+bt*1024+e]=T2[i*LZ+j];
    }
    {
      int a=tid>>5, i=tid&31;
      Cprev[a*LZ+i]=Ck[a*LZ+i];
    }
    if (tid<16){
      float s=0.f;
      #pragma unroll
      for (int i=0;i<DZ;i++) s += Ck[tid*LZ+i]*zpred[i];
      out[off_ap+bt*DA+tid]=s;
    } else if (tid<48){
      zc[tid-16]=zloc[tid-16];
    }
    __syncthreads();
  }
}

extern "C" void kernel_launch(void* const* d_in, const int* in_sizes, int n_in,
                              void* d_out, int out_size, void* d_ws, size_t ws_size,
                              hipStream_t stream) {
  kf_fwd<<<128, NT, 0, stream>>>(
    (const float*)d_in[0],  // a_seq
    (const float*)d_in[1],  // h_obs
    (const float*)d_in[2],  // A_matrices
    (const float*)d_in[3],  // C_matrices
    (const float*)d_in[4],  // B_matrices
    (const float*)d_in[5],  // u_seq
    (const float*)d_in[6],  // mask
    (const float*)d_in[7],  // P_0
    (const float*)d_in[8],  // mat_Q
    (const float*)d_in[9],  // mat_R
    (const float*)d_in[10], // gru_Wx
    (const float*)d_in[11], // gru_Wh
    (const float*)d_in[12], // gru_b
    (const float*)d_in[13], // out_W
    (const float*)d_in[14], // out_b
    (float*)d_out);
}

// Round 4
// 8443.517 us; speedup vs baseline: 1.7154x; 1.1816x over previous
//
#include <hip/hip_runtime.h>
#include <math.h>

#define NT 512

__device__ __forceinline__ float sigf(float x){ return 1.0f/(1.0f+expf(-x)); }

__launch_bounds__(NT, 1)
__global__ void kf_fwd(const float* __restrict__ a_seq, const float* __restrict__ h_obs,
  const float* __restrict__ Amat, const float* __restrict__ Cmat, const float* __restrict__ Bmat,
  const float* __restrict__ u_seq, const float* __restrict__ mask, const float* __restrict__ P0,
  const float* __restrict__ matQ, const float* __restrict__ matR,
  const float* __restrict__ Wx, const float* __restrict__ Wh, const float* __restrict__ gbias,
  const float* __restrict__ outW, const float* __restrict__ outb, float* __restrict__ out)
{
  constexpr int T=256, B=128;
  constexpr int L6=36, L0=20;
  constexpr size_t BT=(size_t)B*T;
  const size_t off_zf=0;
  const size_t off_Pf=off_zf+BT*32;
  const size_t off_zl=off_Pf+BT*1024;
  const size_t off_tr=off_zl+BT*32;
  const size_t off_zp=off_tr+BT*1024;
  const size_t off_Pp=off_zp+BT*32;
  const size_t off_af=off_Pp+BT*1024;
  const size_t off_ap=off_af+BT*16;
  const size_t off_S =off_ap+BT*16;
  const size_t off_al=off_S +BT*256;
  const size_t off_ai=off_al+BT*8;
  const size_t off_R =off_ai+BT*8;
  const size_t off_Q =off_R +256;

  // LDS-resident weights (padded rows, 16B aligned)
  __shared__ __align__(16) float sA[8*32*L6];
  __shared__ __align__(16) float sC[8*16*L6];
  __shared__ __align__(16) float sBm[1024];
  __shared__ __align__(16) float souW[512];
  __shared__ __align__(16) float sgb[192];
  __shared__ __align__(16) float soutb[8];
  // work matrices
  __shared__ __align__(16) float P[32*L6], Ak[32*L6], AkT[32*L6], IKCm[32*L6], IKCT[32*L6];
  __shared__ __align__(16) float T1[32*L6], T3[32*L6], Qm[32*L6], sTril[32*L6];
  __shared__ __align__(16) float Ck[16*L6], CPm[16*L6], KgT[16*L6];
  __shared__ __align__(16) float CPT[32*L0], Kg[32*L0], KgR[32*L0];
  __shared__ __align__(16) float Sm[16*L0], Rm[16*L0], Sinv[16*L0];
  __shared__ __align__(16) float Linv[16*17];
  __shared__ __align__(16) float Bk[128];
  __shared__ __align__(16) float zj[256], aj[128];
  __shared__ __align__(16) float gxp[768], ghlv[192], xin[192];
  __shared__ __align__(16) float zc[32], znew[32], zloc[32], zpred[32], ghs[64];
  __shared__ __align__(16) float ak[16], uk[4], rk[16], ll[8], alpha8[8];
  __shared__ float mval;

  const int tid = threadIdx.x;
  const int b = blockIdx.x;

  // ---------- init ----------
  for (int e=tid; e<8192; e+=NT){ int k=e>>10, i=(e>>5)&31, j=e&31; sA[(k*32+i)*L6+j]=Amat[e]; }
  for (int e=tid; e<4096; e+=NT){ int k=e>>9, a=(e>>5)&15, i=e&31; sC[(k*16+a)*L6+i]=Cmat[e]; }
  for (int e=tid; e<1024; e+=NT) sBm[e]=Bmat[e];
  if (tid<512) souW[tid]=outW[tid];
  if (tid<192) sgb[tid]=gbias[tid];
  if (tid<8)   soutb[tid]=outb[tid];
  for (int e=tid; e<1024; e+=NT){
    int i=e>>5, j=e&31;
    float s=0.f;
    #pragma unroll
    for (int k=0;k<32;k++) s += matQ[i*32+k]*matQ[j*32+k];
    Qm[i*L6+j]=s+(i==j?0.001f:0.f);
    P[i*L6+j]=P0[e];
  }
  for (int e=tid; e<256; e+=NT){
    int i=e>>4, j=e&15;
    float s=0.f;
    #pragma unroll
    for (int k=0;k<16;k++) s += matR[i*16+k]*matR[j*16+k];
    Rm[i*L0+j]=s+(i==j?0.001f:0.f);
  }
  for (int e=tid; e<16*L6; e+=NT) Ck[e]=0.f;   // t=0: aprev = C?@0 = 0, keep finite
  if (tid<32) zc[tid]=0.f;
  if (tid<64) ghs[tid]=0.f;
  if (tid<16) xin[16+tid]=h_obs[b*16+tid];
  __syncthreads();
  if (b==0){
    for (int e=tid;e<256;e+=NT) out[off_R+e]=Rm[(e>>4)*L0+(e&15)];
    for (int e=tid;e<1024;e+=NT) out[off_Q+e]=Qm[(e>>5)*L6+(e&31)];
  }

  for (int t=0;t<T;t++){
    const size_t bt=(size_t)b*T+t;

    // ---- A: loads | zj (f4) | tril[t-1] store | ghl | aprev | xin z-slice | a_pred[t-1] ----
    if (tid<16) ak[tid]=a_seq[bt*16+tid];
    else if (tid<20) uk[tid-16]=u_seq[bt*4+(tid-16)];
    else if (tid==20) mval=mask[bt];
    if (tid<64){
      int k=tid>>3, i0=(tid*4)&31;
      float acc0=0.f,acc1=0.f,acc2=0.f,acc3=0.f;
      #pragma unroll
      for (int q=0;q<8;q++){
        float4 zv=*(const float4*)&zc[q*4];
        float4 a0=*(const float4*)&sA[(k*32+i0+0)*L6+q*4];
        float4 a1=*(const float4*)&sA[(k*32+i0+1)*L6+q*4];
        float4 a2=*(const float4*)&sA[(k*32+i0+2)*L6+q*4];
        float4 a3=*(const float4*)&sA[(k*32+i0+3)*L6+q*4];
        acc0+=a0.x*zv.x+a0.y*zv.y+a0.z*zv.z+a0.w*zv.w;
        acc1+=a1.x*zv.x+a1.y*zv.y+a1.z*zv.z+a1.w*zv.w;
        acc2+=a2.x*zv.x+a2.y*zv.y+a2.z*zv.z+a2.w*zv.w;
        acc3+=a3.x*zv.x+a3.y*zv.y+a3.z*zv.z+a3.w*zv.w;
      }
      *(float4*)&zj[tid*4]=make_float4(acc0,acc1,acc2,acc3);
    } else if (tid<256){
      if (t>0){
        for (int e4=tid-64; e4<256; e4+=192){
          float4 v=*(const float4*)&sTril[(e4>>3)*L6+(e4&7)*4];
          *(float4*)&out[off_tr+(bt-1)*1024+e4*4]=v;
        }
      }
    } else if (tid<448){
      int c=tid-256;
      const float* wp=Wh+c;
      float s=0.f;
      #pragma unroll 16
      for (int i=0;i<64;i++) s+=ghs[i]*wp[i*192];
      ghlv[c]=s;
    } else if (tid<464){
      int a=tid-448;
      float s=0.f;
      #pragma unroll
      for (int i=0;i<32;i++) s+=Ck[a*L6+i]*zc[i];
      xin[a]=s;
    } else if (tid<496){
      xin[32+(tid-464)]=zc[tid-464];
    } else {
      // a_pred for step t-1: Ck and zpred still hold step t-1 values (two
      // barriers behind), phase H overwrites Ck only later this step.
      if (t>0){
        int a=tid-496;
        float s=0.f;
        #pragma unroll
        for (int q=0;q<8;q++){
          float4 cv=*(const float4*)&Ck[a*L6+q*4];
          float4 zv=*(const float4*)&zpred[q*4];
          s+=cv.x*zv.x+cv.y*zv.y+cv.z*zv.z+cv.w*zv.w;
        }
        out[off_ap+(bt-1)*16+a]=s;
      }
    }
    __syncthreads();

    // ---- B: gx partials (inputs 0..63) | aj (f4) ----
    if (tid<384){
      int h=(tid>=192); int c=tid-h*192;
      const float* wp=Wx+(h*32)*192+c;
      float s=0.f;
      #pragma unroll 16
      for (int i=0;i<32;i++) s+=xin[h*32+i]*wp[i*192];
      gxp[h*192+c]=s;
    } else {
      int e=tid-384; int k=e>>4, a=e&15;
      float s=0.f;
      #pragma unroll
      for (int q=0;q<8;q++){
        float4 cv=*(const float4*)&sC[(k*16+a)*L6+q*4];
        float4 zv=*(const float4*)&zj[k*32+q*4];
        s+=cv.x*zv.x+cv.y*zv.y+cv.z*zv.z+cv.w*zv.w;
      }
      aj[e]=s; xin[64+e]=s;
    }
    __syncthreads();

    // ---- D: gx partials (inputs 64..191) | ll + alpha_imm ----
    if (tid<384){
      int h=(tid>=192); int c=tid-h*192;
      const float* wp=Wx+(64+h*64)*192+c;
      float s=0.f;
      #pragma unroll 16
      for (int i=0;i<64;i++) s+=xin[64+h*64+i]*wp[i*192];
      gxp[(2+h)*192+c]=s;
    } else if (tid<392){
      int k=tid-384;
      float s=0.f;
      #pragma unroll
      for (int a=0;a<16;a++){ float d=ak[a]-aj[k*16+a]; s+=d*d; }
      ll[k]=-s;
      float m8=ll[0];
      #pragma unroll
      for (int j=1;j<8;j++) m8=fmaxf(m8,ll[j]);
      float ssum=0.f, ek=0.f;
      #pragma unroll
      for (int j=0;j<8;j++){ float e2=expf(ll[j]-m8); ssum+=e2; if(j==k) ek=e2; }
      out[off_ai+bt*8+k]=ek/ssum*mval;
    }
    __syncthreads();

    // ---- EFG (wave0): gates -> gh -> logits -> alpha ----
    if (tid<64){
      int j=tid;
      float gr=sgb[j]    +gxp[j]    +gxp[192+j]+gxp[384+j]+gxp[576+j];
      float gz=sgb[64+j] +gxp[64+j] +gxp[256+j]+gxp[448+j]+gxp[640+j];
      float gn=sgb[128+j]+gxp[128+j]+gxp[320+j]+gxp[512+j]+gxp[704+j];
      float r =sigf(gr+ghlv[j]);
      float zg=sigf(gz+ghlv[64+j]);
      float n =tanhf(gn+r*ghlv[128+j]);
      ghs[j]=(1.f-zg)*n+zg*ghs[j];
      if (tid<8){
        float s=soutb[tid];
        #pragma unroll
        for (int q=0;q<64;q++) s+=ghs[q]*souW[q*8+tid];
        float m8=s;
        m8=fmaxf(m8,__shfl_xor(m8,1));
        m8=fmaxf(m8,__shfl_xor(m8,2));
        m8=fmaxf(m8,__shfl_xor(m8,4));
        float e2=expf(s-m8);
        float ss=e2;
        ss+=__shfl_xor(ss,1); ss+=__shfl_xor(ss,2); ss+=__shfl_xor(ss,4);
        float av=e2/ss;
        alpha8[tid]=av;
        out[off_al+bt*8+tid]=av;
      }
    }
    __syncthreads();

    // ---- H: blends Ak(+AkT), Ck, Bk ----
    if (tid<256){
      int i=tid>>3, j0=(tid&7)*4;
      float c0=0.f,c1=0.f,c2=0.f,c3=0.f;
      #pragma unroll
      for (int k=0;k<8;k++){
        float al=alpha8[k];
        float4 av=*(const float4*)&sA[(k*32+i)*L6+j0];
        c0+=al*av.x; c1+=al*av.y; c2+=al*av.z; c3+=al*av.w;
      }
      *(float4*)&Ak[i*L6+j0]=make_float4(c0,c1,c2,c3);
      AkT[(j0+0)*L6+i]=c0; AkT[(j0+1)*L6+i]=c1; AkT[(j0+2)*L6+i]=c2; AkT[(j0+3)*L6+i]=c3;
    } else if (tid<384){
      int th=tid-256; int a=th>>3, i0=(th&7)*4;
      float c0=0.f,c1=0.f,c2=0.f,c3=0.f;
      #pragma unroll
      for (int k=0;k<8;k++){
        float al=alpha8[k];
        float4 cv=*(const float4*)&sC[(k*16+a)*L6+i0];
        c0+=al*cv.x; c1+=al*cv.y; c2+=al*cv.z; c3+=al*cv.w;
      }
      *(float4*)&Ck[a*L6+i0]=make_float4(c0,c1,c2,c3);
    } else {
      int e=tid-384;
      float s=0.f;
      #pragma unroll
      for (int k=0;k<8;k++) s+=alpha8[k]*sBm[k*128+e];
      Bk[e]=s;
    }
    __syncthreads();

    // ---- I: CP = Ck@P (+CPT) | znew = Ak@zc ----
    if (tid<128){
      int a=tid>>3, i0=(tid&7)*4;
      float ckr[32];
      #pragma unroll
      for (int q=0;q<8;q++){
        float4 v=*(const float4*)&Ck[a*L6+q*4];
        ckr[q*4+0]=v.x; ckr[q*4+1]=v.y; ckr[q*4+2]=v.z; ckr[q*4+3]=v.w;
      }
      float c0=0.f,c1=0.f,c2=0.f,c3=0.f;
      #pragma unroll
      for (int j=0;j<32;j++){
        float4 pv=*(const float4*)&P[j*L6+i0];
        float w=ckr[j];
        c0+=w*pv.x; c1+=w*pv.y; c2+=w*pv.z; c3+=w*pv.w;
      }
      *(float4*)&CPm[a*L6+i0]=make_float4(c0,c1,c2,c3);
      CPT[(i0+0)*L0+a]=c0; CPT[(i0+1)*L0+a]=c1; CPT[(i0+2)*L0+a]=c2; CPT[(i0+3)*L0+a]=c3;
    } else if (tid<160){
      int i=tid-128;
      float s=0.f;
      #pragma unroll
      for (int j=0;j<32;j++) s+=Ak[i*L6+j]*zc[j];
      znew[i]=s;
    }
    __syncthreads();

    // ---- J: S = CP@Ck^T + R + 1e-4 I | rk ----
    if (tid<64){
      int a=tid>>2, c0=(tid&3)*4;
      float cpr[32];
      #pragma unroll
      for (int q=0;q<8;q++){
        float4 v=*(const float4*)&CPm[a*L6+q*4];
        cpr[q*4+0]=v.x; cpr[q*4+1]=v.y; cpr[q*4+2]=v.z; cpr[q*4+3]=v.w;
      }
      float r0=0.f,r1=0.f,r2=0.f,r3=0.f;
      #pragma unroll
      for (int q=0;q<8;q++){
        float4 v0=*(const float4*)&Ck[(c0+0)*L6+q*4];
        float4 v1=*(const float4*)&Ck[(c0+1)*L6+q*4];
        float4 v2=*(const float4*)&Ck[(c0+2)*L6+q*4];
        float4 v3=*(const float4*)&Ck[(c0+3)*L6+q*4];
        float p0=cpr[q*4+0], p1=cpr[q*4+1], p2=cpr[q*4+2], p3=cpr[q*4+3];
        r0+=p0*v0.x+p1*v0.y+p2*v0.z+p3*v0.w;
        r1+=p0*v1.x+p1*v1.y+p2*v1.z+p3*v1.w;
        r2+=p0*v2.x+p1*v2.y+p2*v2.z+p3*v2.w;
        r3+=p0*v3.x+p1*v3.y+p2*v3.z+p3*v3.w;
      }
      float4 rm=*(const float4*)&Rm[a*L0+c0];
      r0+=rm.x+((a==c0+0)?1e-4f:0.f);
      r1+=rm.y+((a==c0+1)?1e-4f:0.f);
      r2+=rm.z+((a==c0+2)?1e-4f:0.f);
      r3+=rm.w+((a==c0+3)?1e-4f:0.f);
      *(float4*)&Sm[a*L0+c0]=make_float4(r0,r1,r2,r3);
    } else if (tid<80){
      int a=tid-64;
      float s=0.f;
      #pragma unroll
      for (int j=0;j<32;j++) s+=Ck[a*L6+j]*znew[j];
      rk[a]=ak[a]-s;
    }
    __syncthreads();

    // ---- K: wave0 chol16 + Linv + Sinv | S store ----
    if (tid<64){
      int lane=tid; int row=lane<16?lane:15;
      float Sr[16], Lr[16];
      #pragma unroll
      for (int j=0;j<16;j++) Sr[j]=Sm[row*L0+j];
      #pragma unroll
      for (int c=0;c<16;c++){
        float v=Sr[c];
        #pragma unroll
        for (int k=0;k<c;k++) v-=Lr[k]*__shfl(Lr[k],c);
        float d=__shfl(v,c);
        float inv=rsqrtf(d);
        Lr[c]=(lane==c)?d*inv:v*inv;
      }
      float Li[16];
      #pragma unroll
      for (int r=0;r<16;r++){
        float tv=(lane==r)?1.f:0.f;
        #pragma unroll
        for (int k=0;k<r;k++) tv-=__shfl(Lr[k],r)*Li[k];
        Li[r]=tv/__shfl(Lr[r],r);
      }
      if (lane<16){
        #pragma unroll
        for (int r=0;r<16;r++) Linv[r*17+lane]=Li[r];
      }
      #pragma unroll
      for (int q=0;q<4;q++){
        int e=lane+64*q; int a2=e>>4, b2=e&15;
        float s=0.f;
        #pragma unroll
        for (int k=0;k<16;k++) s+=Linv[k*17+a2]*Linv[k*17+b2];
        Sinv[a2*L0+b2]=s;
      }
    } else if (tid<128){
      int th=tid-64;
      float4 v=*(const float4*)&Sm[(th>>2)*L0+(th&3)*4];
      *(float4*)&out[off_S+bt*256+th*4]=v;
    }
    __syncthreads();

    // ---- M: Kg = CP^T @ Sinv (masked) (+KgT) ----
    if (tid<128){
      int i=tid>>2, a0=(tid&3)*4;
      float cpt[16];
      #pragma unroll
      for (int q=0;q<4;q++){
        float4 v=*(const float4*)&CPT[i*L0+q*4];
        cpt[q*4+0]=v.x; cpt[q*4+1]=v.y; cpt[q*4+2]=v.z; cpt[q*4+3]=v.w;
      }
      float c0=0.f,c1=0.f,c2=0.f,c3=0.f;
      #pragma unroll
      for (int b2=0;b2<16;b2++){
        float4 sv=*(const float4*)&Sinv[b2*L0+a0];
        float w=cpt[b2];
        c0+=w*sv.x; c1+=w*sv.y; c2+=w*sv.z; c3+=w*sv.w;
      }
      float m=mval;
      c0*=m; c1*=m; c2*=m; c3*=m;
      *(float4*)&Kg[i*L0+a0]=make_float4(c0,c1,c2,c3);
      KgT[(a0+0)*L6+i]=c0; KgT[(a0+1)*L6+i]=c1; KgT[(a0+2)*L6+i]=c2; KgT[(a0+3)*L6+i]=c3;
    }
    __syncthreads();

    // ---- N: IKC (+IKCT) | KgR | zloc ----
    if (tid<256){
      int i=tid>>3, j0=(tid&7)*4;
      float kgr[16];
      #pragma unroll
      for (int q=0;q<4;q++){
        float4 v=*(const float4*)&Kg[i*L0+q*4];
        kgr[q*4+0]=v.x; kgr[q*4+1]=v.y; kgr[q*4+2]=v.z; kgr[q*4+3]=v.w;
      }
      float c0=(i==j0+0)?1.f:0.f;
      float c1=(i==j0+1)?1.f:0.f;
      float c2=(i==j0+2)?1.f:0.f;
      float c3=(i==j0+3)?1.f:0.f;
      #pragma unroll
      for (int b2=0;b2<16;b2++){
        float4 cv=*(const float4*)&Ck[b2*L6+j0];
        float w=kgr[b2];
        c0-=w*cv.x; c1-=w*cv.y; c2-=w*cv.z; c3-=w*cv.w;
      }
      *(float4*)&IKCm[i*L6+j0]=make_float4(c0,c1,c2,c3);
      IKCT[(j0+0)*L6+i]=c0; IKCT[(j0+1)*L6+i]=c1; IKCT[(j0+2)*L6+i]=c2; IKCT[(j0+3)*L6+i]=c3;
    } else if (tid<384){
      int th=tid-256; int i=th>>2, a0=(th&3)*4;
      float kgr[16];
      #pragma unroll
      for (int q=0;q<4;q++){
        float4 v=*(const float4*)&Kg[i*L0+q*4];
        kgr[q*4+0]=v.x; kgr[q*4+1]=v.y; kgr[q*4+2]=v.z; kgr[q*4+3]=v.w;
      }
      float c0=0.f,c1=0.f,c2=0.f,c3=0.f;
      #pragma unroll
      for (int b2=0;b2<16;b2++){
        float4 rv=*(const float4*)&Rm[b2*L0+a0];
        float w=kgr[b2];
        c0+=w*rv.x; c1+=w*rv.y; c2+=w*rv.z; c3+=w*rv.w;
      }
      *(float4*)&KgR[i*L0+a0]=make_float4(c0,c1,c2,c3);
    } else if (tid<416){
      int i=tid-384;
      float s=znew[i];
      #pragma unroll
      for (int a=0;a<16;a++) s+=Kg[i*L0+a]*rk[a];
      zloc[i]=s;
    }
    __syncthreads();

    // ---- OP: T1 = IKC@P then T3 = T1@IKC^T + KgR@Kg^T + .001I  (wave-private rows) ----
    if (tid<128){
      int rt=tid>>3, ct=tid&7;
      int i0=rt*2, j0=ct*4;
      float w0[32], w1[32];
      #pragma unroll
      for (int q=0;q<8;q++){
        float4 v0=*(const float4*)&IKCm[i0*L6+q*4];
        float4 v1=*(const float4*)&IKCm[(i0+1)*L6+q*4];
        w0[q*4+0]=v0.x; w0[q*4+1]=v0.y; w0[q*4+2]=v0.z; w0[q*4+3]=v0.w;
        w1[q*4+0]=v1.x; w1[q*4+1]=v1.y; w1[q*4+2]=v1.z; w1[q*4+3]=v1.w;
      }
      float a00=0.f,a01=0.f,a02=0.f,a03=0.f,a10=0.f,a11=0.f,a12=0.f,a13=0.f;
      #pragma unroll
      for (int a=0;a<32;a++){
        float4 pv=*(const float4*)&P[a*L6+j0];
        float u0=w0[a], u1=w1[a];
        a00+=u0*pv.x; a01+=u0*pv.y; a02+=u0*pv.z; a03+=u0*pv.w;
        a10+=u1*pv.x; a11+=u1*pv.y; a12+=u1*pv.z; a13+=u1*pv.w;
      }
      *(float4*)&T1[i0*L6+j0]=make_float4(a00,a01,a02,a03);
      *(float4*)&T1[(i0+1)*L6+j0]=make_float4(a10,a11,a12,a13);
      // reload full T1 rows (written by lanes of this same wave, straight-line code)
      #pragma unroll
      for (int q=0;q<8;q++){
        float4 v0=*(const float4*)&T1[i0*L6+q*4];
        float4 v1=*(const float4*)&T1[(i0+1)*L6+q*4];
        w0[q*4+0]=v0.x; w0[q*4+1]=v0.y; w0[q*4+2]=v0.z; w0[q*4+3]=v0.w;
        w1[q*4+0]=v1.x; w1[q*4+1]=v1.y; w1[q*4+2]=v1.z; w1[q*4+3]=v1.w;
      }
      float kr0[16], kr1[16];
      #pragma unroll
      for (int q=0;q<4;q++){
        float4 v0=*(const float4*)&KgR[i0*L0+q*4];
        float4 v1=*(const float4*)&KgR[(i0+1)*L0+q*4];
        kr0[q*4+0]=v0.x; kr0[q*4+1]=v0.y; kr0[q*4+2]=v0.z; kr0[q*4+3]=v0.w;
        kr1[q*4+0]=v1.x; kr1[q*4+1]=v1.y; kr1[q*4+2]=v1.z; kr1[q*4+3]=v1.w;
      }
      a00=0.f;a01=0.f;a02=0.f;a03=0.f;a10=0.f;a11=0.f;a12=0.f;a13=0.f;
      #pragma unroll
      for (int a=0;a<32;a++){
        float4 iv=*(const float4*)&IKCT[a*L6+j0];
        float u0=w0[a], u1=w1[a];
        a00+=u0*iv.x; a01+=u0*iv.y; a02+=u0*iv.z; a03+=u0*iv.w;
        a10+=u1*iv.x; a11+=u1*iv.y; a12+=u1*iv.z; a13+=u1*iv.w;
      }
      #pragma unroll
      for (int b2=0;b2<16;b2++){
        float4 kv=*(const float4*)&KgT[b2*L6+j0];
        float u0=kr0[b2], u1=kr1[b2];
        a00+=u0*kv.x; a01+=u0*kv.y; a02+=u0*kv.z; a03+=u0*kv.w;
        a10+=u1*kv.x; a11+=u1*kv.y; a12+=u1*kv.z; a13+=u1*kv.w;
      }
      float d0[4]={a00,a01,a02,a03}, d1[4]={a10,a11,a12,a13};
      #pragma unroll
      for (int q=0;q<4;q++){
        if (i0==j0+q)   d0[q]+=0.001f;
        if (i0+1==j0+q) d1[q]+=0.001f;
      }
      *(float4*)&T3[i0*L6+j0]=make_float4(d0[0],d0[1],d0[2],d0[3]);
      *(float4*)&T3[(i0+1)*L6+j0]=make_float4(d1[0],d1[1],d1[2],d1[3]);
    }
    __syncthreads();

    // ---- R: wave0 chol32(Pf)->sTril | waves1-2: M3=Ak@Pf, Pp=M3@Ak^T+Q+.001I -> P + store
    //         wave3: Pf/zf/zl/zp stores, zpred, af, zc carry (a_pred deferred: race-free) ----
    {
      int wv=tid>>6, lane=tid&63;
      if (wv==0){
        int row=lane<32?lane:31;
        float Pr[32], Lr[32];
        #pragma unroll
        for (int q=0;q<8;q++){
          float4 v=*(const float4*)&T3[row*L6+q*4];
          Pr[q*4+0]=v.x; Pr[q*4+1]=v.y; Pr[q*4+2]=v.z; Pr[q*4+3]=v.w;
        }
        #pragma unroll
        for (int c=0;c<32;c++){
          float v=Pr[c];
          #pragma unroll
          for (int k=0;k<c;k++) v-=Lr[k]*__shfl(Lr[k],c);
          float d=__shfl(v,c);
          float inv=rsqrtf(d);
          Lr[c]=(lane==c)?d*inv:v*inv;
        }
        if (lane<32){
          #pragma unroll
          for (int q=0;q<8;q++){
            float t0=(q*4+0<=lane)?Lr[q*4+0]:0.f;
            float t1=(q*4+1<=lane)?Lr[q*4+1]:0.f;
            float t2=(q*4+2<=lane)?Lr[q*4+2]:0.f;
            float t3=(q*4+3<=lane)?Lr[q*4+3]:0.f;
            *(float4*)&sTril[lane*L6+q*4]=make_float4(t0,t1,t2,t3);
          }
        }
      } else if (wv<3){
        int th=tid-64;
        int rt=th>>3, ct=th&7;
        int i0=rt*2, j0=ct*4;
        float w0[32], w1[32];
        #pragma unroll
        for (int q=0;q<8;q++){
          float4 v0=*(const float4*)&Ak[i0*L6+q*4];
          float4 v1=*(const float4*)&Ak[(i0+1)*L6+q*4];
          w0[q*4+0]=v0.x; w0[q*4+1]=v0.y; w0[q*4+2]=v0.z; w0[q*4+3]=v0.w;
          w1[q*4+0]=v1.x; w1[q*4+1]=v1.y; w1[q*4+2]=v1.z; w1[q*4+3]=v1.w;
        }
        float a00=0.f,a01=0.f,a02=0.f,a03=0.f,a10=0.f,a11=0.f,a12=0.f,a13=0.f;
        #pragma unroll
        for (int a=0;a<32;a++){
          float4 pv=*(const float4*)&T3[a*L6+j0];
          float u0=w0[a], u1=w1[a];
          a00+=u0*pv.x; a01+=u0*pv.y; a02+=u0*pv.z; a03+=u0*pv.w;
          a10+=u1*pv.x; a11+=u1*pv.y; a12+=u1*pv.z; a13+=u1*pv.w;
        }
        *(float4*)&T1[i0*L6+j0]=make_float4(a00,a01,a02,a03);
        *(float4*)&T1[(i0+1)*L6+j0]=make_float4(a10,a11,a12,a13);
        #pragma unroll
        for (int q=0;q<8;q++){
          float4 v0=*(const float4*)&T1[i0*L6+q*4];
          float4 v1=*(const float4*)&T1[(i0+1)*L6+q*4];
          w0[q*4+0]=v0.x; w0[q*4+1]=v0.y; w0[q*4+2]=v0.z; w0[q*4+3]=v0.w;
          w1[q*4+0]=v1.x; w1[q*4+1]=v1.y; w1[q*4+2]=v1.z; w1[q*4+3]=v1.w;
        }
        float4 q0v=*(const float4*)&Qm[i0*L6+j0];
        float4 q1v=*(const float4*)&Qm[(i0+1)*L6+j0];
        float d0[4]={q0v.x,q0v.y,q0v.z,q0v.w}, d1[4]={q1v.x,q1v.y,q1v.z,q1v.w};
        #pragma unroll
        for (int q=0;q<4;q++){
          if (i0==j0+q)   d0[q]+=0.001f;
          if (i0+1==j0+q) d1[q]+=0.001f;
        }
        #pragma unroll
        for (int a=0;a<32;a++){
          float4 av=*(const float4*)&AkT[a*L6+j0];
          float u0=w0[a], u1=w1[a];
          d0[0]+=u0*av.x; d0[1]+=u0*av.y; d0[2]+=u0*av.z; d0[3]+=u0*av.w;
          d1[0]+=u1*av.x; d1[1]+=u1*av.y; d1[2]+=u1*av.z; d1[3]+=u1*av.w;
        }
        float4 p0=make_float4(d0[0],d0[1],d0[2],d0[3]);
        float4 p1=make_float4(d1[0],d1[1],d1[2],d1[3]);
        *(float4*)&P[i0*L6+j0]=p0;
        *(float4*)&P[(i0+1)*L6+j0]=p1;
        *(float4*)&out[off_Pp+bt*1024+i0*32+j0]=p0;
        *(float4*)&out[off_Pp+bt*1024+(i0+1)*32+j0]=p1;
      } else if (wv==3){
        if (lane<32){
          int row=lane;
          #pragma unroll
          for (int q=0;q<8;q++){
            float4 v=*(const float4*)&T3[row*L6+q*4];
            *(float4*)&out[off_Pf+bt*1024+row*32+q*4]=v;
          }
          float zl=zloc[row];
          out[off_zf+bt*32+row]=zl;
          out[off_zl+bt*32+row]=zl;
          float s=0.f;
          #pragma unroll
          for (int j=0;j<32;j++) s+=Ak[row*L6+j]*zloc[j];
          #pragma unroll
          for (int u2=0;u2<4;u2++) s+=Bk[row*4+u2]*uk[u2];
          zpred[row]=s;
          out[off_zp+bt*32+row]=s;
          zc[row]=zl;
        } else if (lane<48){
          int a=lane-32;
          float s=0.f;
          #pragma unroll
          for (int i=0;i<32;i++) s+=Ck[a*L6+i]*zloc[i];
          out[off_af+bt*16+a]=s;
        }
      }
    }
    __syncthreads();
  }

  // epilogue: tril and a_pred for t = T-1
  {
    const size_t btL=(size_t)b*T+(T-1);
    for (int e4=tid; e4<256; e4+=NT){
      float4 v=*(const float4*)&sTril[(e4>>3)*L6+(e4&7)*4];
      *(float4*)&out[off_tr+btL*1024+e4*4]=v;
    }
    if (tid<16){
      float s=0.f;
      #pragma unroll
      for (int q=0;q<8;q++){
        float4 cv=*(const float4*)&Ck[tid*L6+q*4];
        float4 zv=*(const float4*)&zpred[q*4];
        s+=cv.x*zv.x+cv.y*zv.y+cv.z*zv.z+cv.w*zv.w;
      }
      out[off_ap+btL*16+tid]=s;
    }
  }
}

extern "C" void kernel_launch(void* const* d_in, const int* in_sizes, int n_in,
                              void* d_out, int out_size, void* d_ws, size_t ws_size,
                              hipStream_t stream) {
  kf_fwd<<<128, NT, 0, stream>>>(
    (const float*)d_in[0],  // a_seq
    (const float*)d_in[1],  // h_obs
    (const float*)d_in[2],  // A_matrices
    (const float*)d_in[3],  // C_matrices
    (const float*)d_in[4],  // B_matrices
    (const float*)d_in[5],  // u_seq
    (const float*)d_in[6],  // mask
    (const float*)d_in[7],  // P_0
    (const float*)d_in[8],  // mat_Q
    (const float*)d_in[9],  // mat_R
    (const float*)d_in[10], // gru_Wx
    (const float*)d_in[11], // gru_Wh
    (const float*)d_in[12], // gru_b
    (const float*)d_in[13], // out_W
    (const float*)d_in[14], // out_b
    (float*)d_out);
}